// Round 2
// baseline (752.962 us; speedup 1.0000x reference)
//
#include <hip/hip_runtime.h>
#include <math.h>

#define Bq 8
#define Lq 2048
#define Dq 1024
#define Mq (Bq*Lq)   // 16384 tokens
#define Sq 2048      // S_max
#define SP1 2049     // S_max + 1 (null group row 0)
#define FLAG_CAP 8192
#define MARGIN 0.06f

typedef __attribute__((ext_vector_type(8))) short short8;
typedef __attribute__((ext_vector_type(4))) float f32x4;

// ---- helpers ----
static __device__ __forceinline__ ushort f2bf(float f) {
  union { float f; uint32_t u; } v; v.f = f;
  uint32_t u = v.u;
  return (ushort)((u + 0x7FFF + ((u >> 16) & 1)) >> 16);   // RNE
}

static __device__ __forceinline__ void gload_lds16(const void* gsrc, void* lds) {
  __builtin_amdgcn_global_load_lds(
      (const __attribute__((address_space(1))) uint32_t*)(uintptr_t)gsrc,
      (__attribute__((address_space(3))) uint32_t*)(uint32_t)(uintptr_t)lds,
      16, 0, 0);
}

// ---------------- init logits to b2, zero flag count ----------------
__global__ void init_logits(float* __restrict__ logits, const float* __restrict__ b2,
                            int* __restrict__ count) {
  int i = blockIdx.x * 256 + threadIdx.x;
  if (i < Mq) logits[i] = b2[0];
  if (i == 0) *count = 0;
}

// ---------------- x (f32) -> bf16 ----------------
__global__ void convert_x(const float* __restrict__ x, ushort* __restrict__ xb) {
  int i = blockIdx.x * 256 + threadIdx.x;       // x4 elements
  float4 v = ((const float4*)x)[i];
  ushort4 o;
  o.x = f2bf(v.x); o.y = f2bf(v.y); o.z = f2bf(v.z); o.w = f2bf(v.w);
  ((ushort4*)xb)[i] = o;
}

// ---------------- W1 (f32 [k][n]) -> bf16 transposed [n][k] ----------------
__global__ void convert_w1t(const float* __restrict__ W1, ushort* __restrict__ Wt) {
  __shared__ ushort sh[32][33];
  const int tx = threadIdx.x & 31, ty = threadIdx.x >> 5;   // 32 x 8
  const int k0 = blockIdx.x * 32, n0 = blockIdx.y * 32;
  #pragma unroll
  for (int r = 0; r < 32; r += 8)
    sh[ty + r][tx] = f2bf(W1[(size_t)(k0 + ty + r) * Dq + n0 + tx]);
  __syncthreads();
  #pragma unroll
  for (int r = 0; r < 32; r += 8)
    Wt[(size_t)(n0 + ty + r) * Dq + k0 + tx] = sh[tx][ty + r];
}

// ---------------- MFMA GEMM + fused relu*W2 reduction -> logits ----------------
// C = Xb @ W1 (via Wt = W1^T, bf16), logits[m] += sum_n relu(C[m][n]+b1[n])*W2[n]
__global__ __launch_bounds__(256) void mfma_gemm(
    const ushort* __restrict__ Xb,   // [16384][1024] bf16
    const ushort* __restrict__ Wt,   // [1024][1024] bf16, Wt[n][k]
    const float* __restrict__ b1, const float* __restrict__ W2,
    float* __restrict__ logits)
{
  __shared__ ushort Al[128 * 32];
  __shared__ ushort Bl[128 * 32];
  __shared__ float red[128];
  const int tid = threadIdx.x;
  const int w = tid >> 6, lane = tid & 63;
  const int m0 = blockIdx.x * 128, n0 = blockIdx.y * 128;
  const int wr = w >> 1, wc = w & 1;           // 2x2 wave grid, each 64x64
  const int lr = lane & 15, lq = lane >> 4;    // fragment row, k-quarter

  f32x4 acc[4][4] = {};
  if (tid < 128) red[tid] = 0.f;

  for (int kt = 0; kt < Dq; kt += 32) {
    // stage A and B tiles (rows of 32 bf16 = 64B, linear LDS)
    #pragma unroll
    for (int s = 0; s < 2; ++s) {
      int rbase = s * 64 + w * 16;
      const ushort* srcA = Xb + (size_t)(m0 + rbase + (lane >> 2)) * Dq + kt + (lane & 3) * 8;
      gload_lds16(srcA, &Al[rbase * 32]);
      const ushort* srcB = Wt + (size_t)(n0 + rbase + (lane >> 2)) * Dq + kt + (lane & 3) * 8;
      gload_lds16(srcB, &Bl[rbase * 32]);
    }
    __syncthreads();   // drains vmcnt(0): tiles resident
    short8 a[4], b[4];
    #pragma unroll
    for (int m = 0; m < 4; ++m)
      a[m] = *(const short8*)&Al[(wr * 64 + m * 16 + lr) * 32 + lq * 8];
    #pragma unroll
    for (int n = 0; n < 4; ++n)
      b[n] = *(const short8*)&Bl[(wc * 64 + n * 16 + lr) * 32 + lq * 8];
    #pragma unroll
    for (int m = 0; m < 4; ++m)
      #pragma unroll
      for (int n = 0; n < 4; ++n)
        acc[m][n] = __builtin_amdgcn_mfma_f32_16x16x32_bf16(a[m], b[n], acc[m][n], 0, 0, 0);
    __syncthreads();   // reads done before next stage overwrites
  }

  // epilogue: q[m][reg] = sum over this wave's 64 cols of relu(C+b1)*W2
  float q[4][4];
  #pragma unroll
  for (int m = 0; m < 4; ++m)
    #pragma unroll
    for (int r = 0; r < 4; ++r) q[m][r] = 0.f;
  #pragma unroll
  for (int n = 0; n < 4; ++n) {
    int col = n0 + wc * 64 + n * 16 + lr;
    float bb = b1[col];
    float ww = W2[col];
    #pragma unroll
    for (int m = 0; m < 4; ++m)
      #pragma unroll
      for (int r = 0; r < 4; ++r) {
        float v = acc[m][n][r] + bb;
        v = v > 0.f ? v : 0.f;
        q[m][r] = fmaf(v, ww, q[m][r]);
      }
  }
  #pragma unroll
  for (int m = 0; m < 4; ++m)
    #pragma unroll
    for (int r = 0; r < 4; ++r) {
      float s = q[m][r];
      s += __shfl_xor(s, 1); s += __shfl_xor(s, 2);
      s += __shfl_xor(s, 4); s += __shfl_xor(s, 8);
      if (lr == 0) atomicAdd(&red[wr * 64 + m * 16 + lq * 4 + r], s);
    }
  __syncthreads();
  if (tid < 128) atomicAdd(&logits[m0 + tid], red[tid]);
}

// ---------------- flag tokens with |z| < MARGIN ----------------
__global__ void flag_kernel(const float* __restrict__ logits, const float* __restrict__ noise,
                            int* __restrict__ count, int* __restrict__ list) {
  int i = blockIdx.x * 256 + threadIdx.x;
  float u = noise[i];
  u = fminf(fmaxf(u, 1e-6f), 0.999999f);
  float z = (logits[i] + logf(u)) - log1pf(-u);
  if (fabsf(z) < MARGIN) {
    int id = atomicAdd(count, 1);
    if (id < FLAG_CAP) list[id] = i;
  }
}

// ---------------- exact f32 recompute of flagged logits ----------------
__global__ __launch_bounds__(256) void fix_kernel(
    const float* __restrict__ x, const float* __restrict__ W1,
    const float* __restrict__ b1, const float* __restrict__ W2,
    const float* __restrict__ b2,
    const int* __restrict__ count, const int* __restrict__ list,
    float* __restrict__ logits)
{
  __shared__ float xr[Dq];
  __shared__ float rs[256];
  int cnt = *count; if (cnt > FLAG_CAP) cnt = FLAG_CAP;
  for (int f = blockIdx.x; f < cnt; f += gridDim.x) {
    int tok = list[f];
    __syncthreads();
    for (int k = threadIdx.x; k < Dq; k += 256) xr[k] = x[(size_t)tok * Dq + k];
    __syncthreads();
    float p = 0.f;
    for (int n = threadIdx.x; n < Dq; n += 256) {
      float dot = 0.f;
      for (int k = 0; k < Dq; ++k) dot = fmaf(xr[k], W1[(size_t)k * Dq + n], dot);
      float h = dot + b1[n]; h = h > 0.f ? h : 0.f;
      p = fmaf(h, W2[n], p);
    }
    rs[threadIdx.x] = p;
    __syncthreads();
    for (int s2 = 128; s2 > 0; s2 >>= 1) {
      if (threadIdx.x < s2) rs[threadIdx.x] += rs[threadIdx.x + s2];
      __syncthreads();
    }
    if (threadIdx.x == 0) logits[tok] = rs[0] + b2[0];
  }
}

// ---------------- boundary decision + inclusive scan + segment extents ----------------
__global__ __launch_bounds__(256) void boundary_scan(
    const float* __restrict__ logits, const float* __restrict__ noise,
    int* __restrict__ segup, int* __restrict__ starts, int* __restrict__ ends,
    int* __restrict__ nsegs, int* __restrict__ kb)
{
  const int b = blockIdx.x;
  const int t = threadIdx.x;
  __shared__ unsigned char sh_hard[Lq];
  __shared__ int wsum[4];
  const int l0 = t * 8;
  int h[8];
  int localsum = 0;
  #pragma unroll
  for (int j = 0; j < 8; ++j) {
    int l = l0 + j;
    float u = noise[b * Lq + l];
    u = fminf(fmaxf(u, 1e-6f), 0.999999f);
    float z = (logits[b * Lq + l] + logf(u)) - log1pf(-u);
    int hd = (z > 0.f) ? 1 : 0;
    h[j] = hd;
    sh_hard[l] = (unsigned char)hd;
    localsum += hd;
  }
  int lane = t & 63, w = t >> 6;
  int v = localsum;
  #pragma unroll
  for (int off = 1; off < 64; off <<= 1) {
    int n = __shfl_up(v, off);
    if (lane >= off) v += n;
  }
  if (lane == 63) wsum[w] = v;
  __syncthreads();
  int wpre = 0;
  for (int i = 0; i < w; ++i) wpre += wsum[i];
  int run = wpre + (v - localsum);
  #pragma unroll
  for (int j = 0; j < 8; ++j) {
    int l = l0 + j;
    run += h[j];
    segup[b * Lq + l] = run;
    int sd = run - h[j];
    int hp = (l == 0) ? 1 : (int)sh_hard[l - 1];
    if (hp) starts[b * Sq + sd] = l;
    if (h[j] || l == Lq - 1) ends[b * Sq + sd] = l + 1;
    if (l == Lq - 1) { nsegs[b] = sd + 1; kb[b] = run; }
  }
}

// ---------------- segmented mean-pool -> shortened ----------------
__global__ __launch_bounds__(256) void pool_kernel(
    const float* __restrict__ x, const float* __restrict__ null_group,
    const int* __restrict__ starts, const int* __restrict__ ends,
    const int* __restrict__ nsegs, float* __restrict__ outS)
{
  const int so = blockIdx.x;     // 0..2048 (0 = null group)
  const int b  = blockIdx.y;
  const int d4 = threadIdx.x;
  float4* dst = (float4*)(outS + ((size_t)b * SP1 + so) * Dq) + d4;
  if (so == 0) { *dst = ((const float4*)null_group)[d4]; return; }
  int s = so - 1;
  if (s >= nsegs[b]) { float4 z; z.x = z.y = z.z = z.w = 0.f; *dst = z; return; }
  int st = starts[b * Sq + s], en = ends[b * Sq + s];
  float4 acc; acc.x = acc.y = acc.z = acc.w = 0.f;
  for (int l = st; l < en; ++l) {
    float4 vv = ((const float4*)(x + ((size_t)b * Lq + l) * Dq))[d4];
    acc.x += vv.x; acc.y += vv.y; acc.z += vv.z; acc.w += vv.w;
  }
  float inv = 1.f / (float)(en - st);
  acc.x *= inv; acc.y *= inv; acc.z *= inv; acc.w *= inv;
  *dst = acc;
}

// ---------------- upsample: gather shortened rows ----------------
__global__ __launch_bounds__(256) void upsample_kernel(
    const float* __restrict__ outS, const int* __restrict__ segup,
    float* __restrict__ outU)
{
  const int l = blockIdx.x, b = blockIdx.y;
  const int d4 = threadIdx.x;
  int sg = segup[b * Lq + l];
  ((float4*)(outU + ((size_t)b * Lq + l) * Dq))[d4] =
      ((const float4*)(outS + ((size_t)b * SP1 + sg) * Dq))[d4];
}

// ---------------- binomial consistency loss ----------------
__global__ void loss_kernel(const int* __restrict__ kb, float* __restrict__ out)
{
  int t = threadIdx.x;
  float lp = 0.f;
  if (t < Bq) {
    float k  = (float)kb[t];
    float Lf = (float)Lq;
    lp = lgammaf(Lf + 1.f) - lgammaf(k + 1.f) - lgammaf(Lf - k + 1.f)
       + k * logf(0.25f) + (Lf - k) * log1pf(-0.25f);
  }
  #pragma unroll
  for (int off = 32; off > 0; off >>= 1) lp += __shfl_down(lp, off);
  if (t == 0) out[0] = -(lp / (float)Bq) / (float)Lq;
}

extern "C" void kernel_launch(void* const* d_in, const int* in_sizes, int n_in,
                              void* d_out, int out_size, void* d_ws, size_t ws_size,
                              hipStream_t stream) {
  const float* x     = (const float*)d_in[0];
  const float* noise = (const float*)d_in[1];
  const float* W1    = (const float*)d_in[2];
  const float* b1    = (const float*)d_in[3];
  const float* W2    = (const float*)d_in[4];
  const float* b2    = (const float*)d_in[5];
  const float* ng    = (const float*)d_in[6];

  float* outS = (float*)d_out;                       // [8, 2049, 1024]
  float* outU = outS + (size_t)Bq * SP1 * Dq;        // [8, 2048, 1024]
  float* outL = outU + (size_t)Bq * Lq * Dq;         // scalar

  // big scratch lives in the outU region (fully overwritten by upsample at the end)
  ushort* xb = (ushort*)outU;                                   // 32 MB bf16 x
  ushort* wt = (ushort*)((char*)outU + (size_t)33554432);       // 2 MB bf16 W1^T

  char* ws = (char*)d_ws;
  float* logits = (float*)(ws);                      // 16384 f32
  int*   segup  = (int*)(ws + 65536);                // 16384 i32
  int*   starts = (int*)(ws + 131072);               // 8*2048 i32
  int*   ends   = (int*)(ws + 196608);               // 8*2048 i32
  int*   nsegs  = (int*)(ws + 262144);               // 8 i32
  int*   kb     = (int*)(ws + 262400);               // 8 i32
  int*   count  = (int*)(ws + 262656);               // 1 i32
  int*   list   = (int*)(ws + 262912);               // FLAG_CAP i32

  init_logits<<<Mq / 256, 256, 0, stream>>>(logits, b2, count);
  convert_x<<<(Mq * Dq / 4) / 256, 256, 0, stream>>>(x, xb);
  convert_w1t<<<dim3(32, 32), 256, 0, stream>>>(W1, wt);
  mfma_gemm<<<dim3(Mq / 128, Dq / 128), 256, 0, stream>>>(xb, wt, b1, W2, logits);
  flag_kernel<<<Mq / 256, 256, 0, stream>>>(logits, noise, count, list);
  fix_kernel<<<128, 256, 0, stream>>>(x, W1, b1, W2, b2, count, list, logits);
  boundary_scan<<<Bq, 256, 0, stream>>>(logits, noise, segup, starts, ends, nsegs, kb);
  pool_kernel<<<dim3(SP1, Bq), 256, 0, stream>>>(x, ng, starts, ends, nsegs, outS);
  upsample_kernel<<<dim3(Lq, Bq), 256, 0, stream>>>(outS, segup, outU);
  loss_kernel<<<1, 64, 0, stream>>>(kb, outL);
}

// Round 6
// 364.621 us; speedup vs baseline: 2.0651x; 2.0651x over previous
//
#include <hip/hip_runtime.h>
#include <math.h>

#define Bq 8
#define Lq 2048
#define Dq 1024
#define Mq (Bq*Lq)   // 16384 tokens
#define Sq 2048      // S_max
#define SP1 2049     // S_max + 1 (null group row 0)
#define FLAG_CAP 8192
#define MARGIN 0.06f

typedef __attribute__((ext_vector_type(8))) short short8;
typedef __attribute__((ext_vector_type(4))) float f32x4;

// ---- helpers ----
static __device__ __forceinline__ ushort f2bf(float f) {
  union { float f; uint32_t u; } v; v.f = f;
  uint32_t u = v.u;
  return (ushort)((u + 0x7FFF + ((u >> 16) & 1)) >> 16);   // RNE
}

static __device__ __forceinline__ void gload_lds16(const void* gsrc, void* lds) {
  __builtin_amdgcn_global_load_lds(
      (const __attribute__((address_space(1))) uint32_t*)(uintptr_t)gsrc,
      (__attribute__((address_space(3))) uint32_t*)(uint32_t)(uintptr_t)lds,
      16, 0, 0);
}

// ---------------- init logits to b2, zero flag count ----------------
__global__ void init_logits(float* __restrict__ logits, const float* __restrict__ b2,
                            int* __restrict__ count) {
  int i = blockIdx.x * 256 + threadIdx.x;
  if (i < Mq) logits[i] = b2[0];
  if (i == 0) *count = 0;
}

// ---------------- x (f32) -> bf16 ----------------
__global__ void convert_x(const float* __restrict__ x, ushort* __restrict__ xb) {
  int i = blockIdx.x * 256 + threadIdx.x;       // x4 elements
  float4 v = ((const float4*)x)[i];
  ushort4 o;
  o.x = f2bf(v.x); o.y = f2bf(v.y); o.z = f2bf(v.z); o.w = f2bf(v.w);
  ((ushort4*)xb)[i] = o;
}

// ---------------- W1 (f32 [k][n]) -> bf16 transposed [n][k] ----------------
__global__ void convert_w1t(const float* __restrict__ W1, ushort* __restrict__ Wt) {
  __shared__ ushort sh[32][33];
  const int tx = threadIdx.x & 31, ty = threadIdx.x >> 5;   // 32 x 8
  const int k0 = blockIdx.x * 32, n0 = blockIdx.y * 32;
  #pragma unroll
  for (int r = 0; r < 32; r += 8)
    sh[ty + r][tx] = f2bf(W1[(size_t)(k0 + ty + r) * Dq + n0 + tx]);
  __syncthreads();
  #pragma unroll
  for (int r = 0; r < 32; r += 8)
    Wt[(size_t)(n0 + ty + r) * Dq + k0 + tx] = sh[tx][ty + r];
}

// ---------------- MFMA GEMM + fused relu*W2 reduction -> logits ----------------
__global__ __launch_bounds__(256) void mfma_gemm(
    const ushort* __restrict__ Xb,   // [16384][1024] bf16
    const ushort* __restrict__ Wt,   // [1024][1024] bf16, Wt[n][k]
    const float* __restrict__ b1, const float* __restrict__ W2,
    float* __restrict__ logits)
{
  __shared__ ushort Al[128 * 32];
  __shared__ ushort Bl[128 * 32];
  __shared__ float red[128];
  const int tid = threadIdx.x;
  const int w = tid >> 6, lane = tid & 63;
  const int m0 = blockIdx.x * 128, n0 = blockIdx.y * 128;
  const int wr = w >> 1, wc = w & 1;           // 2x2 wave grid, each 64x64
  const int lr = lane & 15, lq = lane >> 4;    // fragment row, k-quarter

  f32x4 acc[4][4] = {};
  if (tid < 128) red[tid] = 0.f;

  for (int kt = 0; kt < Dq; kt += 32) {
    #pragma unroll
    for (int s = 0; s < 2; ++s) {
      int rbase = s * 64 + w * 16;
      const ushort* srcA = Xb + (size_t)(m0 + rbase + (lane >> 2)) * Dq + kt + (lane & 3) * 8;
      gload_lds16(srcA, &Al[rbase * 32]);
      const ushort* srcB = Wt + (size_t)(n0 + rbase + (lane >> 2)) * Dq + kt + (lane & 3) * 8;
      gload_lds16(srcB, &Bl[rbase * 32]);
    }
    __syncthreads();
    short8 a[4], b[4];
    #pragma unroll
    for (int m = 0; m < 4; ++m)
      a[m] = *(const short8*)&Al[(wr * 64 + m * 16 + lr) * 32 + lq * 8];
    #pragma unroll
    for (int n = 0; n < 4; ++n)
      b[n] = *(const short8*)&Bl[(wc * 64 + n * 16 + lr) * 32 + lq * 8];
    #pragma unroll
    for (int m = 0; m < 4; ++m)
      #pragma unroll
      for (int n = 0; n < 4; ++n)
        acc[m][n] = __builtin_amdgcn_mfma_f32_16x16x32_bf16(a[m], b[n], acc[m][n], 0, 0, 0);
    __syncthreads();
  }

  float q[4][4];
  #pragma unroll
  for (int m = 0; m < 4; ++m)
    #pragma unroll
    for (int r = 0; r < 4; ++r) q[m][r] = 0.f;
  #pragma unroll
  for (int n = 0; n < 4; ++n) {
    int col = n0 + wc * 64 + n * 16 + lr;
    float bb = b1[col];
    float ww = W2[col];
    #pragma unroll
    for (int m = 0; m < 4; ++m)
      #pragma unroll
      for (int r = 0; r < 4; ++r) {
        float v = acc[m][n][r] + bb;
        v = v > 0.f ? v : 0.f;
        q[m][r] = fmaf(v, ww, q[m][r]);
      }
  }
  #pragma unroll
  for (int m = 0; m < 4; ++m)
    #pragma unroll
    for (int r = 0; r < 4; ++r) {
      float s = q[m][r];
      s += __shfl_xor(s, 1); s += __shfl_xor(s, 2);
      s += __shfl_xor(s, 4); s += __shfl_xor(s, 8);
      if (lr == 0) atomicAdd(&red[wr * 64 + m * 16 + lq * 4 + r], s);
    }
  __syncthreads();
  if (tid < 128) atomicAdd(&logits[m0 + tid], red[tid]);
}

// ---------------- flag tokens with |z| < MARGIN ----------------
__global__ void flag_kernel(const float* __restrict__ logits, const float* __restrict__ noise,
                            int* __restrict__ count, int* __restrict__ list) {
  int i = blockIdx.x * 256 + threadIdx.x;
  float u = noise[i];
  u = fminf(fmaxf(u, 1e-6f), 0.999999f);
  float z = (logits[i] + logf(u)) - log1pf(-u);
  if (fabsf(z) < MARGIN) {
    int id = atomicAdd(count, 1);
    if (id < FLAG_CAP) list[id] = i;
  }
}

// ---------------- gather flagged x rows into compact Abuf; reset logits to b2 ----------------
__global__ void gather_kernel(const float* __restrict__ x, const int* __restrict__ count,
                              const int* __restrict__ list, const float* __restrict__ b2,
                              float* __restrict__ Abuf, float* __restrict__ logits) {
  int cnt = *count; if (cnt > FLAG_CAP) cnt = FLAG_CAP;
  if (cnt <= 0) return;
  float b2v = b2[0];
  for (int f = blockIdx.x; f < cnt; f += gridDim.x) {
    int tok = list[f];
    ((float4*)(Abuf + (size_t)f * Dq))[threadIdx.x] =
        ((const float4*)(x + (size_t)tok * Dq))[threadIdx.x];
    if (threadIdx.x == 0) logits[tok] = b2v;
  }
}

// ---------------- batched exact f32 recompute: logits[tok] += relu(A@W1+b1)@W2 ----------------
// tiles: 32 tokens x 128 n per block; K chunked by 32 through LDS
__global__ __launch_bounds__(256) void fix_gemm(
    const float* __restrict__ Abuf, const float* __restrict__ W1,
    const float* __restrict__ b1, const float* __restrict__ W2,
    const int* __restrict__ count, const int* __restrict__ list,
    float* __restrict__ logits)
{
  __shared__ float Asl[32][33];
  __shared__ float Bsl[32][128];
  int cnt = *count; if (cnt > FLAG_CAP) cnt = FLAG_CAP;
  if (cnt <= 0) return;
  int tiles_m = (cnt + 31) >> 5;
  int total = tiles_m * 8;
  const int tid = threadIdx.x;
  const int tx = tid & 31, ty = tid >> 5;
  for (int t = blockIdx.x; t < total; t += gridDim.x) {
    int m0 = (t >> 3) * 32, n0 = (t & 7) * 128;
    float C[4][4] = {};
    for (int k0 = 0; k0 < Dq; k0 += 32) {
      __syncthreads();
      {  // stage A chunk (32 m x 32 k), transposed to [k][m]
        int mr = tid >> 3, kf = tid & 7;
        float4 va = *(const float4*)(Abuf + (size_t)(m0 + mr) * Dq + k0 + kf * 4);
        Asl[kf*4+0][mr] = va.x; Asl[kf*4+1][mr] = va.y;
        Asl[kf*4+2][mr] = va.z; Asl[kf*4+3][mr] = va.w;
      }
      #pragma unroll
      for (int s = 0; s < 4; ++s) {  // stage B chunk (32 k x 128 n)
        int slot = tid + s * 256;
        int kb = slot >> 5, nf = slot & 31;
        *(float4*)(&Bsl[kb][nf*4]) =
            *(const float4*)(W1 + (size_t)(k0 + kb) * Dq + n0 + nf * 4);
      }
      __syncthreads();
      #pragma unroll
      for (int k = 0; k < 32; ++k) {
        float a[4], b[4];
        #pragma unroll
        for (int i = 0; i < 4; ++i) a[i] = Asl[k][ty*4+i];
        #pragma unroll
        for (int j = 0; j < 4; ++j) b[j] = Bsl[k][tx + 32*j];
        #pragma unroll
        for (int i = 0; i < 4; ++i)
          #pragma unroll
          for (int j = 0; j < 4; ++j)
            C[i][j] = fmaf(a[i], b[j], C[i][j]);
      }
    }
    float p[4] = {0,0,0,0};
    #pragma unroll
    for (int j = 0; j < 4; ++j) {
      int gn = n0 + tx + 32*j;
      float bb = b1[gn], ww = W2[gn];
      #pragma unroll
      for (int i = 0; i < 4; ++i) {
        float v = C[i][j] + bb; v = v > 0.f ? v : 0.f;
        p[i] = fmaf(v, ww, p[i]);
      }
    }
    #pragma unroll
    for (int i = 0; i < 4; ++i) {
      float s = p[i];
      s += __shfl_xor(s, 1); s += __shfl_xor(s, 2); s += __shfl_xor(s, 4);
      s += __shfl_xor(s, 8); s += __shfl_xor(s, 16);
      int m = m0 + ty*4 + i;
      if (tx == 0 && m < cnt) atomicAdd(&logits[list[m]], s);
    }
    __syncthreads();
  }
}

// ---------------- boundary decision + inclusive scan + segment extents ----------------
__global__ __launch_bounds__(256) void boundary_scan(
    const float* __restrict__ logits, const float* __restrict__ noise,
    int* __restrict__ segup, int* __restrict__ starts, int* __restrict__ ends,
    int* __restrict__ nsegs, int* __restrict__ kb)
{
  const int b = blockIdx.x;
  const int t = threadIdx.x;
  __shared__ unsigned char sh_hard[Lq];
  __shared__ int wsum[4];
  const int l0 = t * 8;
  int h[8];
  int localsum = 0;
  #pragma unroll
  for (int j = 0; j < 8; ++j) {
    int l = l0 + j;
    float u = noise[b * Lq + l];
    u = fminf(fmaxf(u, 1e-6f), 0.999999f);
    float z = (logits[b * Lq + l] + logf(u)) - log1pf(-u);
    int hd = (z > 0.f) ? 1 : 0;
    h[j] = hd;
    sh_hard[l] = (unsigned char)hd;
    localsum += hd;
  }
  int lane = t & 63, w = t >> 6;
  int v = localsum;
  #pragma unroll
  for (int off = 1; off < 64; off <<= 1) {
    int n = __shfl_up(v, off);
    if (lane >= off) v += n;
  }
  if (lane == 63) wsum[w] = v;
  __syncthreads();
  int wpre = 0;
  for (int i = 0; i < w; ++i) wpre += wsum[i];
  int run = wpre + (v - localsum);
  #pragma unroll
  for (int j = 0; j < 8; ++j) {
    int l = l0 + j;
    run += h[j];
    segup[b * Lq + l] = run;
    int sd = run - h[j];
    int hp = (l == 0) ? 1 : (int)sh_hard[l - 1];
    if (hp) starts[b * Sq + sd] = l;
    if (h[j] || l == Lq - 1) ends[b * Sq + sd] = l + 1;
    if (l == Lq - 1) { nsegs[b] = sd + 1; kb[b] = run; }
  }
}

// ---------------- segmented mean-pool -> shortened ----------------
__global__ __launch_bounds__(256) void pool_kernel(
    const float* __restrict__ x, const float* __restrict__ null_group,
    const int* __restrict__ starts, const int* __restrict__ ends,
    const int* __restrict__ nsegs, float* __restrict__ outS)
{
  const int so = blockIdx.x;     // 0..2048 (0 = null group)
  const int b  = blockIdx.y;
  const int d4 = threadIdx.x;
  float4* dst = (float4*)(outS + ((size_t)b * SP1 + so) * Dq) + d4;
  if (so == 0) { *dst = ((const float4*)null_group)[d4]; return; }
  int s = so - 1;
  if (s >= nsegs[b]) { float4 z; z.x = z.y = z.z = z.w = 0.f; *dst = z; return; }
  int st = starts[b * Sq + s], en = ends[b * Sq + s];
  float4 acc; acc.x = acc.y = acc.z = acc.w = 0.f;
  for (int l = st; l < en; ++l) {
    float4 vv = ((const float4*)(x + ((size_t)b * Lq + l) * Dq))[d4];
    acc.x += vv.x; acc.y += vv.y; acc.z += vv.z; acc.w += vv.w;
  }
  float inv = 1.f / (float)(en - st);
  acc.x *= inv; acc.y *= inv; acc.z *= inv; acc.w *= inv;
  *dst = acc;
}

// ---------------- upsample: gather shortened rows ----------------
__global__ __launch_bounds__(256) void upsample_kernel(
    const float* __restrict__ outS, const int* __restrict__ segup,
    float* __restrict__ outU)
{
  const int l = blockIdx.x, b = blockIdx.y;
  const int d4 = threadIdx.x;
  int sg = segup[b * Lq + l];
  ((float4*)(outU + ((size_t)b * Lq + l) * Dq))[d4] =
      ((const float4*)(outS + ((size_t)b * SP1 + sg) * Dq))[d4];
}

// ---------------- binomial consistency loss ----------------
__global__ void loss_kernel(const int* __restrict__ kb, float* __restrict__ out)
{
  int t = threadIdx.x;
  float lp = 0.f;
  if (t < Bq) {
    float k  = (float)kb[t];
    float Lf = (float)Lq;
    lp = lgammaf(Lf + 1.f) - lgammaf(k + 1.f) - lgammaf(Lf - k + 1.f)
       + k * logf(0.25f) + (Lf - k) * log1pf(-0.25f);
  }
  #pragma unroll
  for (int off = 32; off > 0; off >>= 1) lp += __shfl_down(lp, off);
  if (t == 0) out[0] = -(lp / (float)Bq) / (float)Lq;
}

extern "C" void kernel_launch(void* const* d_in, const int* in_sizes, int n_in,
                              void* d_out, int out_size, void* d_ws, size_t ws_size,
                              hipStream_t stream) {
  const float* x     = (const float*)d_in[0];
  const float* noise = (const float*)d_in[1];
  const float* W1    = (const float*)d_in[2];
  const float* b1    = (const float*)d_in[3];
  const float* W2    = (const float*)d_in[4];
  const float* b2    = (const float*)d_in[5];
  const float* ng    = (const float*)d_in[6];

  float* outS = (float*)d_out;                       // [8, 2049, 1024]
  float* outU = outS + (size_t)Bq * SP1 * Dq;        // [8, 2048, 1024]
  float* outL = outU + (size_t)Bq * Lq * Dq;         // scalar

  // big scratch in d_out regions (both fully rewritten later):
  ushort* xb   = (ushort*)outU;                                 // 32 MB bf16 x (in outU, consumed before upsample writes)
  ushort* wt   = (ushort*)((char*)outU + (size_t)33554432);     // 2 MB bf16 W1^T
  float*  Abuf = outS;                                          // 32 MB gathered rows (in outS, consumed before pool writes)

  char* ws = (char*)d_ws;
  float* logits = (float*)(ws);                      // 16384 f32
  int*   segup  = (int*)(ws + 65536);                // 16384 i32
  int*   starts = (int*)(ws + 131072);               // 8*2048 i32
  int*   ends   = (int*)(ws + 196608);               // 8*2048 i32
  int*   nsegs  = (int*)(ws + 262144);               // 8 i32
  int*   kb     = (int*)(ws + 262400);               // 8 i32
  int*   count  = (int*)(ws + 262656);               // 1 i32
  int*   list   = (int*)(ws + 262912);               // FLAG_CAP i32

  init_logits<<<Mq / 256, 256, 0, stream>>>(logits, b2, count);
  convert_x<<<(Mq * Dq / 4) / 256, 256, 0, stream>>>(x, xb);
  convert_w1t<<<dim3(32, 32), 256, 0, stream>>>(W1, wt);
  mfma_gemm<<<dim3(Mq / 128, Dq / 128), 256, 0, stream>>>(xb, wt, b1, W2, logits);
  flag_kernel<<<Mq / 256, 256, 0, stream>>>(logits, noise, count, list);
  gather_kernel<<<512, 256, 0, stream>>>(x, count, list, b2, Abuf, logits);
  fix_gemm<<<1024, 256, 0, stream>>>(Abuf, W1, b1, W2, count, list, logits);
  boundary_scan<<<Bq, 256, 0, stream>>>(logits, noise, segup, starts, ends, nsegs, kb);
  pool_kernel<<<dim3(SP1, Bq), 256, 0, stream>>>(x, ng, starts, ends, nsegs, outS);
  upsample_kernel<<<dim3(Lq, Bq), 256, 0, stream>>>(outS, segup, outU);
  loss_kernel<<<1, 64, 0, stream>>>(kb, outL);
}

// Round 7
// 311.905 us; speedup vs baseline: 2.4141x; 1.1690x over previous
//
#include <hip/hip_runtime.h>
#include <math.h>

#define Bq 8
#define Lq 2048
#define Dq 1024
#define Mq (Bq*Lq)   // 16384 tokens
#define Sq 2048      // S_max
#define SP1 2049     // S_max + 1 (null group row 0)
#define FLAG_CAP 1024
#define KSLICES 8    // k-slice width = 128
#define MARGIN 0.06f

typedef __attribute__((ext_vector_type(8))) short short8;
typedef __attribute__((ext_vector_type(4))) float f32x4;

// ---- helpers ----
static __device__ __forceinline__ ushort f2bf(float f) {
  union { float f; uint32_t u; } v; v.f = f;
  uint32_t u = v.u;
  return (ushort)((u + 0x7FFF + ((u >> 16) & 1)) >> 16);   // RNE
}

static __device__ __forceinline__ void gload_lds16(const void* gsrc, void* lds) {
  __builtin_amdgcn_global_load_lds(
      (const __attribute__((address_space(1))) uint32_t*)(uintptr_t)gsrc,
      (__attribute__((address_space(3))) uint32_t*)(uint32_t)(uintptr_t)lds,
      16, 0, 0);
}

// ---------------- init logits to b2, zero flag count ----------------
__global__ void init_logits(float* __restrict__ logits, const float* __restrict__ b2,
                            int* __restrict__ count) {
  int i = blockIdx.x * 256 + threadIdx.x;
  if (i < Mq) logits[i] = b2[0];
  if (i == 0) *count = 0;
}

// ---------------- x (f32) -> bf16 ----------------
__global__ void convert_x(const float* __restrict__ x, ushort* __restrict__ xb) {
  int i = blockIdx.x * 256 + threadIdx.x;       // x4 elements
  float4 v = ((const float4*)x)[i];
  ushort4 o;
  o.x = f2bf(v.x); o.y = f2bf(v.y); o.z = f2bf(v.z); o.w = f2bf(v.w);
  ((ushort4*)xb)[i] = o;
}

// ---------------- W1 (f32 [k][n]) -> bf16 transposed [n][k] ----------------
__global__ void convert_w1t(const float* __restrict__ W1, ushort* __restrict__ Wt) {
  __shared__ ushort sh[32][33];
  const int tx = threadIdx.x & 31, ty = threadIdx.x >> 5;   // 32 x 8
  const int k0 = blockIdx.x * 32, n0 = blockIdx.y * 32;
  #pragma unroll
  for (int r = 0; r < 32; r += 8)
    sh[ty + r][tx] = f2bf(W1[(size_t)(k0 + ty + r) * Dq + n0 + tx]);
  __syncthreads();
  #pragma unroll
  for (int r = 0; r < 32; r += 8)
    Wt[(size_t)(n0 + ty + r) * Dq + k0 + tx] = sh[tx][ty + r];
}

// ---------------- MFMA GEMM + fused relu*W2 reduction -> logits ----------------
__global__ __launch_bounds__(256) void mfma_gemm(
    const ushort* __restrict__ Xb,   // [16384][1024] bf16
    const ushort* __restrict__ Wt,   // [1024][1024] bf16, Wt[n][k]
    const float* __restrict__ b1, const float* __restrict__ W2,
    float* __restrict__ logits)
{
  __shared__ ushort Al[128 * 32];
  __shared__ ushort Bl[128 * 32];
  __shared__ float red[128];
  const int tid = threadIdx.x;
  const int w = tid >> 6, lane = tid & 63;
  const int m0 = blockIdx.x * 128, n0 = blockIdx.y * 128;
  const int wr = w >> 1, wc = w & 1;           // 2x2 wave grid, each 64x64
  const int lr = lane & 15, lq = lane >> 4;    // fragment row, k-quarter

  f32x4 acc[4][4] = {};
  if (tid < 128) red[tid] = 0.f;

  for (int kt = 0; kt < Dq; kt += 32) {
    #pragma unroll
    for (int s = 0; s < 2; ++s) {
      int rbase = s * 64 + w * 16;
      const ushort* srcA = Xb + (size_t)(m0 + rbase + (lane >> 2)) * Dq + kt + (lane & 3) * 8;
      gload_lds16(srcA, &Al[rbase * 32]);
      const ushort* srcB = Wt + (size_t)(n0 + rbase + (lane >> 2)) * Dq + kt + (lane & 3) * 8;
      gload_lds16(srcB, &Bl[rbase * 32]);
    }
    __syncthreads();
    short8 a[4], b[4];
    #pragma unroll
    for (int m = 0; m < 4; ++m)
      a[m] = *(const short8*)&Al[(wr * 64 + m * 16 + lr) * 32 + lq * 8];
    #pragma unroll
    for (int n = 0; n < 4; ++n)
      b[n] = *(const short8*)&Bl[(wc * 64 + n * 16 + lr) * 32 + lq * 8];
    #pragma unroll
    for (int m = 0; m < 4; ++m)
      #pragma unroll
      for (int n = 0; n < 4; ++n)
        acc[m][n] = __builtin_amdgcn_mfma_f32_16x16x32_bf16(a[m], b[n], acc[m][n], 0, 0, 0);
    __syncthreads();
  }

  float q[4][4];
  #pragma unroll
  for (int m = 0; m < 4; ++m)
    #pragma unroll
    for (int r = 0; r < 4; ++r) q[m][r] = 0.f;
  #pragma unroll
  for (int n = 0; n < 4; ++n) {
    int col = n0 + wc * 64 + n * 16 + lr;
    float bb = b1[col];
    float ww = W2[col];
    #pragma unroll
    for (int m = 0; m < 4; ++m)
      #pragma unroll
      for (int r = 0; r < 4; ++r) {
        float v = acc[m][n][r] + bb;
        v = v > 0.f ? v : 0.f;
        q[m][r] = fmaf(v, ww, q[m][r]);
      }
  }
  #pragma unroll
  for (int m = 0; m < 4; ++m)
    #pragma unroll
    for (int r = 0; r < 4; ++r) {
      float s = q[m][r];
      s += __shfl_xor(s, 1); s += __shfl_xor(s, 2);
      s += __shfl_xor(s, 4); s += __shfl_xor(s, 8);
      if (lr == 0) atomicAdd(&red[wr * 64 + m * 16 + lq * 4 + r], s);
    }
  __syncthreads();
  if (tid < 128) atomicAdd(&logits[m0 + tid], red[tid]);
}

// ---------------- flag tokens with |z| < MARGIN ----------------
__global__ void flag_kernel(const float* __restrict__ logits, const float* __restrict__ noise,
                            int* __restrict__ count, int* __restrict__ list) {
  int i = blockIdx.x * 256 + threadIdx.x;
  float u = noise[i];
  u = fminf(fmaxf(u, 1e-6f), 0.999999f);
  float z = (logits[i] + logf(u)) - log1pf(-u);
  if (fabsf(z) < MARGIN) {
    int id = atomicAdd(count, 1);
    if (id < FLAG_CAP) list[id] = i;
  }
}

// ---------------- fix phase 1: K-split partial dots ----------------
// blocks: (m-tile of 32 tokens) x (8 n-slices of 128) x (KSLICES k-slices of 128)
// hbuf[ks][f][n] = sum_{k in slice ks} x[list[f]][k] * W1[k][n]   (f32, no atomics)
__global__ __launch_bounds__(256) void fix_part1(
    const float* __restrict__ x, const float* __restrict__ W1,
    const int* __restrict__ count, const int* __restrict__ list,
    float* __restrict__ hbuf)
{
  __shared__ float Asl[32][33];
  __shared__ float Bsl[32][128];
  int cnt = *count; if (cnt > FLAG_CAP) cnt = FLAG_CAP;
  if (cnt <= 0) return;
  int tiles_m = (cnt + 31) >> 5;
  int total = tiles_m * 8 * KSLICES;
  const int tid = threadIdx.x;
  const int tx = tid & 31, ty = tid >> 5;
  for (int t = blockIdx.x; t < total; t += gridDim.x) {
    int m0 = (t / (8 * KSLICES)) * 32;
    int n0 = ((t / KSLICES) & 7) * 128;
    int kbase = (t % KSLICES) * (Dq / KSLICES);
    float C[4][4] = {};
    for (int kc = 0; kc < Dq / KSLICES; kc += 32) {
      int k0 = kbase + kc;
      __syncthreads();
      {  // stage A chunk (32 tokens x 32 k), transposed to [k][m]
        int mr = tid >> 3, kf = tid & 7;
        int fidx = m0 + mr; if (fidx >= cnt) fidx = cnt - 1;
        int tok = list[fidx];
        float4 va = *(const float4*)(x + (size_t)tok * Dq + k0 + kf * 4);
        Asl[kf*4+0][mr] = va.x; Asl[kf*4+1][mr] = va.y;
        Asl[kf*4+2][mr] = va.z; Asl[kf*4+3][mr] = va.w;
      }
      #pragma unroll
      for (int s = 0; s < 4; ++s) {  // stage B chunk (32 k x 128 n)
        int slot = tid + s * 256;
        int kb = slot >> 5, nf = slot & 31;
        *(float4*)(&Bsl[kb][nf*4]) =
            *(const float4*)(W1 + (size_t)(k0 + kb) * Dq + n0 + nf * 4);
      }
      __syncthreads();
      #pragma unroll
      for (int k = 0; k < 32; ++k) {
        float a[4], b[4];
        #pragma unroll
        for (int i = 0; i < 4; ++i) a[i] = Asl[k][ty*4+i];
        #pragma unroll
        for (int j = 0; j < 4; ++j) b[j] = Bsl[k][tx + 32*j];
        #pragma unroll
        for (int i = 0; i < 4; ++i)
          #pragma unroll
          for (int j = 0; j < 4; ++j)
            C[i][j] = fmaf(a[i], b[j], C[i][j]);
      }
    }
    // store partial tile (rows beyond cnt land in scratch rows < FLAG_CAP: harmless)
    int ks = t % KSLICES;
    #pragma unroll
    for (int i = 0; i < 4; ++i) {
      int f = m0 + ty*4 + i;
      float* dst = hbuf + ((size_t)ks * FLAG_CAP + f) * Dq + n0 + tx;
      #pragma unroll
      for (int j = 0; j < 4; ++j) dst[32*j] = C[i][j];
    }
    __syncthreads();
  }
}

// ---------------- fix phase 2: sum partials, relu*W2 reduce, write exact logit ----------------
__global__ __launch_bounds__(256) void fix_part2(
    const float* __restrict__ hbuf, const float* __restrict__ b1,
    const float* __restrict__ W2, const float* __restrict__ b2,
    const int* __restrict__ count, const int* __restrict__ list,
    float* __restrict__ logits)
{
  __shared__ float rs[4];
  int cnt = *count; if (cnt > FLAG_CAP) cnt = FLAG_CAP;
  const int tid = threadIdx.x;
  const int lane = tid & 63, w = tid >> 6;
  float b2v = b2[0];
  for (int f = blockIdx.x; f < cnt; f += gridDim.x) {
    int n = tid * 4;
    float4 h = {0.f, 0.f, 0.f, 0.f};
    #pragma unroll
    for (int ks = 0; ks < KSLICES; ++ks) {
      float4 pv = *(const float4*)(hbuf + ((size_t)ks * FLAG_CAP + f) * Dq + n);
      h.x += pv.x; h.y += pv.y; h.z += pv.z; h.w += pv.w;
    }
    float4 bb = *(const float4*)(b1 + n);
    float4 ww = *(const float4*)(W2 + n);
    float p = 0.f;
    float v;
    v = h.x + bb.x; v = v > 0.f ? v : 0.f; p = fmaf(v, ww.x, p);
    v = h.y + bb.y; v = v > 0.f ? v : 0.f; p = fmaf(v, ww.y, p);
    v = h.z + bb.z; v = v > 0.f ? v : 0.f; p = fmaf(v, ww.z, p);
    v = h.w + bb.w; v = v > 0.f ? v : 0.f; p = fmaf(v, ww.w, p);
    #pragma unroll
    for (int off = 32; off > 0; off >>= 1) p += __shfl_xor(p, off);
    if (lane == 0) rs[w] = p;
    __syncthreads();
    if (tid == 0) logits[list[f]] = b2v + rs[0] + rs[1] + rs[2] + rs[3];
    __syncthreads();
  }
}

// ---------------- boundary decision + inclusive scan + segment extents ----------------
__global__ __launch_bounds__(256) void boundary_scan(
    const float* __restrict__ logits, const float* __restrict__ noise,
    int* __restrict__ segup, int* __restrict__ starts, int* __restrict__ ends,
    int* __restrict__ nsegs, int* __restrict__ kb)
{
  const int b = blockIdx.x;
  const int t = threadIdx.x;
  __shared__ unsigned char sh_hard[Lq];
  __shared__ int wsum[4];
  const int l0 = t * 8;
  int h[8];
  int localsum = 0;
  #pragma unroll
  for (int j = 0; j < 8; ++j) {
    int l = l0 + j;
    float u = noise[b * Lq + l];
    u = fminf(fmaxf(u, 1e-6f), 0.999999f);
    float z = (logits[b * Lq + l] + logf(u)) - log1pf(-u);
    int hd = (z > 0.f) ? 1 : 0;
    h[j] = hd;
    sh_hard[l] = (unsigned char)hd;
    localsum += hd;
  }
  int lane = t & 63, w = t >> 6;
  int v = localsum;
  #pragma unroll
  for (int off = 1; off < 64; off <<= 1) {
    int n = __shfl_up(v, off);
    if (lane >= off) v += n;
  }
  if (lane == 63) wsum[w] = v;
  __syncthreads();
  int wpre = 0;
  for (int i = 0; i < w; ++i) wpre += wsum[i];
  int run = wpre + (v - localsum);
  #pragma unroll
  for (int j = 0; j < 8; ++j) {
    int l = l0 + j;
    run += h[j];
    segup[b * Lq + l] = run;
    int sd = run - h[j];
    int hp = (l == 0) ? 1 : (int)sh_hard[l - 1];
    if (hp) starts[b * Sq + sd] = l;
    if (h[j] || l == Lq - 1) ends[b * Sq + sd] = l + 1;
    if (l == Lq - 1) { nsegs[b] = sd + 1; kb[b] = run; }
  }
}

// ---------------- segmented mean-pool -> shortened ----------------
__global__ __launch_bounds__(256) void pool_kernel(
    const float* __restrict__ x, const float* __restrict__ null_group,
    const int* __restrict__ starts, const int* __restrict__ ends,
    const int* __restrict__ nsegs, float* __restrict__ outS)
{
  const int so = blockIdx.x;     // 0..2048 (0 = null group)
  const int b  = blockIdx.y;
  const int d4 = threadIdx.x;
  float4* dst = (float4*)(outS + ((size_t)b * SP1 + so) * Dq) + d4;
  if (so == 0) { *dst = ((const float4*)null_group)[d4]; return; }
  int s = so - 1;
  if (s >= nsegs[b]) { float4 z; z.x = z.y = z.z = z.w = 0.f; *dst = z; return; }
  int st = starts[b * Sq + s], en = ends[b * Sq + s];
  float4 acc; acc.x = acc.y = acc.z = acc.w = 0.f;
  for (int l = st; l < en; ++l) {
    float4 vv = ((const float4*)(x + ((size_t)b * Lq + l) * Dq))[d4];
    acc.x += vv.x; acc.y += vv.y; acc.z += vv.z; acc.w += vv.w;
  }
  float inv = 1.f / (float)(en - st);
  acc.x *= inv; acc.y *= inv; acc.z *= inv; acc.w *= inv;
  *dst = acc;
}

// ---------------- upsample: gather shortened rows ----------------
__global__ __launch_bounds__(256) void upsample_kernel(
    const float* __restrict__ outS, const int* __restrict__ segup,
    float* __restrict__ outU)
{
  const int l = blockIdx.x, b = blockIdx.y;
  const int d4 = threadIdx.x;
  int sg = segup[b * Lq + l];
  ((float4*)(outU + ((size_t)b * Lq + l) * Dq))[d4] =
      ((const float4*)(outS + ((size_t)b * SP1 + sg) * Dq))[d4];
}

// ---------------- binomial consistency loss ----------------
__global__ void loss_kernel(const int* __restrict__ kb, float* __restrict__ out)
{
  int t = threadIdx.x;
  float lp = 0.f;
  if (t < Bq) {
    float k  = (float)kb[t];
    float Lf = (float)Lq;
    lp = lgammaf(Lf + 1.f) - lgammaf(k + 1.f) - lgammaf(Lf - k + 1.f)
       + k * logf(0.25f) + (Lf - k) * log1pf(-0.25f);
  }
  #pragma unroll
  for (int off = 32; off > 0; off >>= 1) lp += __shfl_down(lp, off);
  if (t == 0) out[0] = -(lp / (float)Bq) / (float)Lq;
}

extern "C" void kernel_launch(void* const* d_in, const int* in_sizes, int n_in,
                              void* d_out, int out_size, void* d_ws, size_t ws_size,
                              hipStream_t stream) {
  const float* x     = (const float*)d_in[0];
  const float* noise = (const float*)d_in[1];
  const float* W1    = (const float*)d_in[2];
  const float* b1    = (const float*)d_in[3];
  const float* W2    = (const float*)d_in[4];
  const float* b2    = (const float*)d_in[5];
  const float* ng    = (const float*)d_in[6];

  float* outS = (float*)d_out;                       // [8, 2049, 1024]
  float* outU = outS + (size_t)Bq * SP1 * Dq;        // [8, 2048, 1024]
  float* outL = outU + (size_t)Bq * Lq * Dq;         // scalar

  // big scratch in d_out regions (both fully rewritten later):
  ushort* xb   = (ushort*)outU;                                 // 32 MB bf16 x (in outU, consumed before upsample writes)
  ushort* wt   = (ushort*)((char*)outU + (size_t)33554432);     // 2 MB bf16 W1^T
  float*  hbuf = outS;                                          // 32 MB K-split partials (in outS, consumed before pool writes)

  char* ws = (char*)d_ws;
  float* logits = (float*)(ws);                      // 16384 f32
  int*   segup  = (int*)(ws + 65536);                // 16384 i32
  int*   starts = (int*)(ws + 131072);               // 8*2048 i32
  int*   ends   = (int*)(ws + 196608);               // 8*2048 i32
  int*   nsegs  = (int*)(ws + 262144);               // 8 i32
  int*   kb     = (int*)(ws + 262400);               // 8 i32
  int*   count  = (int*)(ws + 262656);               // 1 i32
  int*   list   = (int*)(ws + 262912);               // FLAG_CAP i32

  init_logits<<<Mq / 256, 256, 0, stream>>>(logits, b2, count);
  convert_x<<<(Mq * Dq / 4) / 256, 256, 0, stream>>>(x, xb);
  convert_w1t<<<dim3(32, 32), 256, 0, stream>>>(W1, wt);
  mfma_gemm<<<dim3(Mq / 128, Dq / 128), 256, 0, stream>>>(xb, wt, b1, W2, logits);
  flag_kernel<<<Mq / 256, 256, 0, stream>>>(logits, noise, count, list);
  fix_part1<<<2048, 256, 0, stream>>>(x, W1, count, list, hbuf);
  fix_part2<<<1024, 256, 0, stream>>>(hbuf, b1, W2, b2, count, list, logits);
  boundary_scan<<<Bq, 256, 0, stream>>>(logits, noise, segup, starts, ends, nsegs, kb);
  pool_kernel<<<dim3(SP1, Bq), 256, 0, stream>>>(x, ng, starts, ends, nsegs, outS);
  upsample_kernel<<<dim3(Lq, Bq), 256, 0, stream>>>(outS, segup, outU);
  loss_kernel<<<1, 64, 0, stream>>>(kb, outL);
}

// Round 8
// 306.059 us; speedup vs baseline: 2.4602x; 1.0191x over previous
//
#include <hip/hip_runtime.h>
#include <math.h>

#define Bq 8
#define Lq 2048
#define Dq 1024
#define Mq (Bq*Lq)   // 16384 tokens
#define Sq 2048      // S_max
#define SP1 2049     // S_max + 1 (null group row 0)
#define FLAG_CAP 1024
#define KSLICES 8    // k-slice width = 128
#define MARGIN 0.06f

typedef __attribute__((ext_vector_type(8))) short short8;
typedef __attribute__((ext_vector_type(4))) float f32x4;

// ---- helpers ----
static __device__ __forceinline__ ushort f2bf(float f) {
  union { float f; uint32_t u; } v; v.f = f;
  uint32_t u = v.u;
  return (ushort)((u + 0x7FFF + ((u >> 16) & 1)) >> 16);   // RNE
}

static __device__ __forceinline__ void gload_lds16(const void* gsrc, void* lds) {
  __builtin_amdgcn_global_load_lds(
      (const __attribute__((address_space(1))) uint32_t*)(uintptr_t)gsrc,
      (__attribute__((address_space(3))) uint32_t*)(uint32_t)(uintptr_t)lds,
      16, 0, 0);
}

// ---------------- fused: x->bf16, W1->bf16^T, logits=b2, count=0 ----------------
__global__ void convert_fused(const float* __restrict__ x, const float* __restrict__ W1,
                              const float* __restrict__ b2,
                              ushort* __restrict__ xb, ushort* __restrict__ wt,
                              float* __restrict__ logits, int* __restrict__ count) {
  int bid = blockIdx.x;
  if (bid < 16384) {                       // x conversion: 16384 blocks x 256 float4
    int i = bid * 256 + threadIdx.x;
    float4 v = ((const float4*)x)[i];
    ushort4 o;
    o.x = f2bf(v.x); o.y = f2bf(v.y); o.z = f2bf(v.z); o.w = f2bf(v.w);
    ((ushort4*)xb)[i] = o;
    if (i < Mq) logits[i] = b2[0];
    if (i == 0) *count = 0;
  } else {                                 // W1^T tiles: 1024 blocks of 32x32
    __shared__ ushort sh[32][33];
    int t = bid - 16384;
    const int tx = threadIdx.x & 31, ty = threadIdx.x >> 5;   // 32 x 8
    const int k0 = (t >> 5) * 32, n0 = (t & 31) * 32;
    #pragma unroll
    for (int r = 0; r < 32; r += 8)
      sh[ty + r][tx] = f2bf(W1[(size_t)(k0 + ty + r) * Dq + n0 + tx]);
    __syncthreads();
    #pragma unroll
    for (int r = 0; r < 32; r += 8)
      wt[(size_t)(n0 + ty + r) * Dq + k0 + tx] = sh[tx][ty + r];
  }
}

// ---------------- MFMA GEMM + fused relu*W2 reduction -> logits ----------------
// grid (8 n-tiles fast, 128 m-tiles slow): cohorts share A panel; Wt (2MB) L2-resident
__global__ __launch_bounds__(256) void mfma_gemm(
    const ushort* __restrict__ Xb,   // [16384][1024] bf16
    const ushort* __restrict__ Wt,   // [1024][1024] bf16, Wt[n][k]
    const float* __restrict__ b1, const float* __restrict__ W2,
    float* __restrict__ logits)
{
  __shared__ ushort Al[128 * 32];
  __shared__ ushort Bl[128 * 32];
  __shared__ float red[128];
  const int tid = threadIdx.x;
  const int w = tid >> 6, lane = tid & 63;
  const int m0 = blockIdx.y * 128, n0 = blockIdx.x * 128;
  const int wr = w >> 1, wc = w & 1;           // 2x2 wave grid, each 64x64
  const int lr = lane & 15, lq = lane >> 4;    // fragment row, k-quarter

  f32x4 acc[4][4] = {};
  if (tid < 128) red[tid] = 0.f;

  for (int kt = 0; kt < Dq; kt += 32) {
    #pragma unroll
    for (int s = 0; s < 2; ++s) {
      int rbase = s * 64 + w * 16;
      const ushort* srcA = Xb + (size_t)(m0 + rbase + (lane >> 2)) * Dq + kt + (lane & 3) * 8;
      gload_lds16(srcA, &Al[rbase * 32]);
      const ushort* srcB = Wt + (size_t)(n0 + rbase + (lane >> 2)) * Dq + kt + (lane & 3) * 8;
      gload_lds16(srcB, &Bl[rbase * 32]);
    }
    __syncthreads();
    short8 a[4], b[4];
    #pragma unroll
    for (int m = 0; m < 4; ++m)
      a[m] = *(const short8*)&Al[(wr * 64 + m * 16 + lr) * 32 + lq * 8];
    #pragma unroll
    for (int n = 0; n < 4; ++n)
      b[n] = *(const short8*)&Bl[(wc * 64 + n * 16 + lr) * 32 + lq * 8];
    #pragma unroll
    for (int m = 0; m < 4; ++m)
      #pragma unroll
      for (int n = 0; n < 4; ++n)
        acc[m][n] = __builtin_amdgcn_mfma_f32_16x16x32_bf16(a[m], b[n], acc[m][n], 0, 0, 0);
    __syncthreads();
  }

  float q[4][4];
  #pragma unroll
  for (int m = 0; m < 4; ++m)
    #pragma unroll
    for (int r = 0; r < 4; ++r) q[m][r] = 0.f;
  #pragma unroll
  for (int n = 0; n < 4; ++n) {
    int col = n0 + wc * 64 + n * 16 + lr;
    float bb = b1[col];
    float ww = W2[col];
    #pragma unroll
    for (int m = 0; m < 4; ++m)
      #pragma unroll
      for (int r = 0; r < 4; ++r) {
        float v = acc[m][n][r] + bb;
        v = v > 0.f ? v : 0.f;
        q[m][r] = fmaf(v, ww, q[m][r]);
      }
  }
  #pragma unroll
  for (int m = 0; m < 4; ++m)
    #pragma unroll
    for (int r = 0; r < 4; ++r) {
      float s = q[m][r];
      s += __shfl_xor(s, 1); s += __shfl_xor(s, 2);
      s += __shfl_xor(s, 4); s += __shfl_xor(s, 8);
      if (lr == 0) atomicAdd(&red[wr * 64 + m * 16 + lq * 4 + r], s);
    }
  __syncthreads();
  if (tid < 128) atomicAdd(&logits[m0 + tid], red[tid]);
}

// ---------------- flag tokens with |z| < MARGIN ----------------
__global__ void flag_kernel(const float* __restrict__ logits, const float* __restrict__ noise,
                            int* __restrict__ count, int* __restrict__ list) {
  int i = blockIdx.x * 256 + threadIdx.x;
  float u = noise[i];
  u = fminf(fmaxf(u, 1e-6f), 0.999999f);
  float z = (logits[i] + logf(u)) - log1pf(-u);
  if (fabsf(z) < MARGIN) {
    int id = atomicAdd(count, 1);
    if (id < FLAG_CAP) list[id] = i;
  }
}

// ---------------- fix phase 1: K-split partial dots ----------------
__global__ __launch_bounds__(256) void fix_part1(
    const float* __restrict__ x, const float* __restrict__ W1,
    const int* __restrict__ count, const int* __restrict__ list,
    float* __restrict__ hbuf)
{
  __shared__ float Asl[32][33];
  __shared__ float Bsl[32][128];
  int cnt = *count; if (cnt > FLAG_CAP) cnt = FLAG_CAP;
  if (cnt <= 0) return;
  int tiles_m = (cnt + 31) >> 5;
  int total = tiles_m * 8 * KSLICES;
  const int tid = threadIdx.x;
  const int tx = tid & 31, ty = tid >> 5;
  for (int t = blockIdx.x; t < total; t += gridDim.x) {
    int m0 = (t / (8 * KSLICES)) * 32;
    int n0 = ((t / KSLICES) & 7) * 128;
    int kbase = (t % KSLICES) * (Dq / KSLICES);
    float C[4][4] = {};
    for (int kc = 0; kc < Dq / KSLICES; kc += 32) {
      int k0 = kbase + kc;
      __syncthreads();
      {  // stage A chunk (32 tokens x 32 k), transposed to [k][m]
        int mr = tid >> 3, kf = tid & 7;
        int fidx = m0 + mr; if (fidx >= cnt) fidx = cnt - 1;
        int tok = list[fidx];
        float4 va = *(const float4*)(x + (size_t)tok * Dq + k0 + kf * 4);
        Asl[kf*4+0][mr] = va.x; Asl[kf*4+1][mr] = va.y;
        Asl[kf*4+2][mr] = va.z; Asl[kf*4+3][mr] = va.w;
      }
      #pragma unroll
      for (int s = 0; s < 4; ++s) {  // stage B chunk (32 k x 128 n)
        int slot = tid + s * 256;
        int kb2 = slot >> 5, nf = slot & 31;
        *(float4*)(&Bsl[kb2][nf*4]) =
            *(const float4*)(W1 + (size_t)(k0 + kb2) * Dq + n0 + nf * 4);
      }
      __syncthreads();
      #pragma unroll
      for (int k = 0; k < 32; ++k) {
        float a[4], b[4];
        #pragma unroll
        for (int i = 0; i < 4; ++i) a[i] = Asl[k][ty*4+i];
        #pragma unroll
        for (int j = 0; j < 4; ++j) b[j] = Bsl[k][tx + 32*j];
        #pragma unroll
        for (int i = 0; i < 4; ++i)
          #pragma unroll
          for (int j = 0; j < 4; ++j)
            C[i][j] = fmaf(a[i], b[j], C[i][j]);
      }
    }
    int ks = t % KSLICES;
    #pragma unroll
    for (int i = 0; i < 4; ++i) {
      int f = m0 + ty*4 + i;
      float* dst = hbuf + ((size_t)ks * FLAG_CAP + f) * Dq + n0 + tx;
      #pragma unroll
      for (int j = 0; j < 4; ++j) dst[32*j] = C[i][j];
    }
    __syncthreads();
  }
}

// ---------------- fix phase 2: sum partials, relu*W2 reduce, write exact logit ----------------
__global__ __launch_bounds__(256) void fix_part2(
    const float* __restrict__ hbuf, const float* __restrict__ b1,
    const float* __restrict__ W2, const float* __restrict__ b2,
    const int* __restrict__ count, const int* __restrict__ list,
    float* __restrict__ logits)
{
  __shared__ float rs[4];
  int cnt = *count; if (cnt > FLAG_CAP) cnt = FLAG_CAP;
  const int tid = threadIdx.x;
  const int lane = tid & 63, w = tid >> 6;
  float b2v = b2[0];
  for (int f = blockIdx.x; f < cnt; f += gridDim.x) {
    int n = tid * 4;
    float4 h = {0.f, 0.f, 0.f, 0.f};
    #pragma unroll
    for (int ks = 0; ks < KSLICES; ++ks) {
      float4 pv = *(const float4*)(hbuf + ((size_t)ks * FLAG_CAP + f) * Dq + n);
      h.x += pv.x; h.y += pv.y; h.z += pv.z; h.w += pv.w;
    }
    float4 bb = *(const float4*)(b1 + n);
    float4 ww = *(const float4*)(W2 + n);
    float p = 0.f;
    float v;
    v = h.x + bb.x; v = v > 0.f ? v : 0.f; p = fmaf(v, ww.x, p);
    v = h.y + bb.y; v = v > 0.f ? v : 0.f; p = fmaf(v, ww.y, p);
    v = h.z + bb.z; v = v > 0.f ? v : 0.f; p = fmaf(v, ww.z, p);
    v = h.w + bb.w; v = v > 0.f ? v : 0.f; p = fmaf(v, ww.w, p);
    #pragma unroll
    for (int off = 32; off > 0; off >>= 1) p += __shfl_xor(p, off);
    if (lane == 0) rs[w] = p;
    __syncthreads();
    if (tid == 0) logits[list[f]] = b2v + rs[0] + rs[1] + rs[2] + rs[3];
    __syncthreads();
  }
}

// ---------------- boundary decision + scan + segment extents + boundary positions ----------------
__global__ __launch_bounds__(256) void boundary_scan(
    const float* __restrict__ logits, const float* __restrict__ noise,
    int* __restrict__ starts, int* __restrict__ ends, int* __restrict__ ubs,
    int* __restrict__ nsegs, int* __restrict__ kb)
{
  const int b = blockIdx.x;
  const int t = threadIdx.x;
  __shared__ unsigned char sh_hard[Lq];
  __shared__ int wsum[4];
  const int l0 = t * 8;
  int h[8];
  int localsum = 0;
  #pragma unroll
  for (int j = 0; j < 8; ++j) {
    int l = l0 + j;
    float u = noise[b * Lq + l];
    u = fminf(fmaxf(u, 1e-6f), 0.999999f);
    float z = (logits[b * Lq + l] + logf(u)) - log1pf(-u);
    int hd = (z > 0.f) ? 1 : 0;
    h[j] = hd;
    sh_hard[l] = (unsigned char)hd;
    localsum += hd;
  }
  int lane = t & 63, w = t >> 6;
  int v = localsum;
  #pragma unroll
  for (int off = 1; off < 64; off <<= 1) {
    int n = __shfl_up(v, off);
    if (lane >= off) v += n;
  }
  if (lane == 63) wsum[w] = v;
  __syncthreads();
  int wpre = 0;
  for (int i = 0; i < w; ++i) wpre += wsum[i];
  int run = wpre + (v - localsum);
  if (t == 0) ubs[b * SP1] = 0;
  #pragma unroll
  for (int j = 0; j < 8; ++j) {
    int l = l0 + j;
    run += h[j];
    int sd = run - h[j];                 // exclusive cumsum = downsample segment id
    if (h[j]) ubs[b * SP1 + run] = l;    // first token with segup == run
    int hp = (l == 0) ? 1 : (int)sh_hard[l - 1];
    if (hp) starts[b * Sq + sd] = l;
    if (h[j] || l == Lq - 1) ends[b * Sq + sd] = l + 1;
    if (l == Lq - 1) { nsegs[b] = sd + 1; kb[b] = run; }
  }
}

// ---------------- fused pool + upsample-scatter ----------------
// block (so, b): compute outS row so; scatter it to outU rows [ubs[so], ubs[so+1])
__global__ __launch_bounds__(256) void pool_up(
    const float* __restrict__ x, const float* __restrict__ null_group,
    const int* __restrict__ starts, const int* __restrict__ ends,
    const int* __restrict__ nsegs, const int* __restrict__ ubs,
    const int* __restrict__ kb,
    float* __restrict__ outS, float* __restrict__ outU)
{
  const int so = blockIdx.x;     // 0..2048 (0 = null group)
  const int b  = blockIdx.y;
  const int d4 = threadIdx.x;
  float4 val;
  if (so == 0) {
    val = ((const float4*)null_group)[d4];
  } else {
    int s = so - 1;
    if (s >= nsegs[b]) {
      val.x = val.y = val.z = val.w = 0.f;
    } else {
      int st = starts[b * Sq + s], en = ends[b * Sq + s];
      float4 acc; acc.x = acc.y = acc.z = acc.w = 0.f;
      for (int l = st; l < en; ++l) {
        float4 vv = ((const float4*)(x + ((size_t)b * Lq + l) * Dq))[d4];
        acc.x += vv.x; acc.y += vv.y; acc.z += vv.z; acc.w += vv.w;
      }
      float inv = 1.f / (float)(en - st);
      val.x = acc.x * inv; val.y = acc.y * inv; val.z = acc.z * inv; val.w = acc.w * inv;
    }
  }
  ((float4*)(outS + ((size_t)b * SP1 + so) * Dq))[d4] = val;
  // scatter to upsampled rows (tokens with segup == so form a contiguous range)
  int K = kb[b];
  if (so <= K) {
    int rs = ubs[b * SP1 + so];
    int re = (so < K) ? ubs[b * SP1 + so + 1] : Lq;
    for (int l = rs; l < re; ++l)
      ((float4*)(outU + ((size_t)b * Lq + l) * Dq))[d4] = val;
  }
}

// ---------------- binomial consistency loss ----------------
__global__ void loss_kernel(const int* __restrict__ kb, float* __restrict__ out)
{
  int t = threadIdx.x;
  float lp = 0.f;
  if (t < Bq) {
    float k  = (float)kb[t];
    float Lf = (float)Lq;
    lp = lgammaf(Lf + 1.f) - lgammaf(k + 1.f) - lgammaf(Lf - k + 1.f)
       + k * logf(0.25f) + (Lf - k) * log1pf(-0.25f);
  }
  #pragma unroll
  for (int off = 32; off > 0; off >>= 1) lp += __shfl_down(lp, off);
  if (t == 0) out[0] = -(lp / (float)Bq) / (float)Lq;
}

extern "C" void kernel_launch(void* const* d_in, const int* in_sizes, int n_in,
                              void* d_out, int out_size, void* d_ws, size_t ws_size,
                              hipStream_t stream) {
  const float* x     = (const float*)d_in[0];
  const float* noise = (const float*)d_in[1];
  const float* W1    = (const float*)d_in[2];
  const float* b1    = (const float*)d_in[3];
  const float* W2    = (const float*)d_in[4];
  const float* b2    = (const float*)d_in[5];
  const float* ng    = (const float*)d_in[6];

  float* outS = (float*)d_out;                       // [8, 2049, 1024]
  float* outU = outS + (size_t)Bq * SP1 * Dq;        // [8, 2048, 1024]
  float* outL = outU + (size_t)Bq * Lq * Dq;         // scalar

  // big scratch in d_out regions (both fully rewritten later):
  ushort* xb   = (ushort*)outU;                                 // 32 MB bf16 x (consumed by gemm before pool_up writes outU)
  ushort* wt   = (ushort*)((char*)outU + (size_t)33554432);     // 2 MB bf16 W1^T
  float*  hbuf = outS;                                          // 32 MB K-split partials (consumed before pool_up writes outS)

  char* ws = (char*)d_ws;
  float* logits = (float*)(ws);                      // 16384 f32           @ 0
  int*   starts = (int*)(ws + 65536);                // 8*2048 i32          @ 64K
  int*   ends   = (int*)(ws + 131072);               // 8*2048 i32          @ 128K
  int*   ubs    = (int*)(ws + 196608);               // 8*2049 i32          @ 192K
  int*   nsegs  = (int*)(ws + 266240);               // 8 i32
  int*   kb     = (int*)(ws + 266496);               // 8 i32
  int*   count  = (int*)(ws + 266752);               // 1 i32
  int*   list   = (int*)(ws + 267008);               // FLAG_CAP i32

  convert_fused<<<16384 + 1024, 256, 0, stream>>>(x, W1, b2, xb, wt, logits, count);
  mfma_gemm<<<dim3(Dq / 128, Mq / 128), 256, 0, stream>>>(xb, wt, b1, W2, logits);
  flag_kernel<<<Mq / 256, 256, 0, stream>>>(logits, noise, count, list);
  fix_part1<<<2048, 256, 0, stream>>>(x, W1, count, list, hbuf);
  fix_part2<<<1024, 256, 0, stream>>>(hbuf, b1, W2, b2, count, list, logits);
  boundary_scan<<<Bq, 256, 0, stream>>>(logits, noise, starts, ends, ubs, nsegs, kb);
  pool_up<<<dim3(SP1, Bq), 256, 0, stream>>>(x, ng, starts, ends, nsegs, ubs, kb, outS, outU);
  loss_kernel<<<1, 64, 0, stream>>>(kb, outL);
}